// Round 7
// baseline (121.405 us; speedup 1.0000x reference)
//
#include <hip/hip_runtime.h>
#include <hip/hip_bf16.h>
#include <math.h>

#define NPTS 131072
#define DIM 32
#define MCL 256
#define NSTEP 18           // symmetric packing: 1 sq + 15 pair + 1 pair/lin + 1 lin/pad
#define BPTS 128           // points per block
#define THREADS 256

typedef __attribute__((ext_vector_type(8))) short s8v;    // 8 bf16 bit-patterns
typedef __attribute__((ext_vector_type(4))) float f32x4;

__device__ __forceinline__ unsigned short f2bf(float f) {
    union { float f; unsigned u; } v; v.f = f;
    unsigned r = v.u + 0x7fffu + ((v.u >> 16) & 1u);   // RNE
    return (unsigned short)(r >> 16);
}

// ---------------------------------------------------------------------------
// prep (256 threads/cluster): symmetric-packed G (bf16):
//  step 0           : c = E[k][k]                (squares; E = LL^T - I)
//  steps 1..15      : c = 2*E[k][(k+s)&31]       (pairs, circular diff s)
//  step 16, k<16    : c = 2*E[k][k+16]           (diff-16 pairs)
//  step 16, k>=16   : c = -2*Ac[k-16]            (linear)
//  step 17, k<16    : c = -2*Ac[k+16]            (linear)
//  step 17, k>=16   : c = 0                      (pad)
// G addr (shorts): s*8192 + (m>>4)*512 + (k>>3)*128 + (m&15)*8 + (k&7)
// logdet: register GE on wave 0 (col-per-lane, unrolled, no pivot).
// ---------------------------------------------------------------------------
__global__ __launch_bounds__(256) void gmm_prep(
    const float* __restrict__ center,
    const float* __restrict__ L,
    const float* __restrict__ weight,
    short* __restrict__ G,
    float* __restrict__ cst)
{
    const int m = blockIdx.x;
    const int t = threadIdx.x;
    __shared__ float Ls[DIM][DIM + 1];
    __shared__ float As[DIM][DIM + 1];
    __shared__ float Acs[DIM];
    __shared__ float red[DIM];

    const float* Lm = L + m * DIM * DIM;
    for (int k = t; k < DIM * DIM; k += 256)
        Ls[k >> 5][k & 31] = Lm[k];
    __syncthreads();

    // A = L L^T  (4 elems/thread)
    for (int idx = t; idx < DIM * DIM; idx += 256) {
        const int j = idx >> 5, l = idx & 31;
        float a = 0.f;
        #pragma unroll
        for (int d = 0; d < DIM; ++d) a = fmaf(Ls[j][d], Ls[l][d], a);
        As[j][l] = a;
    }
    __syncthreads();

    if (t < DIM) {
        float a = 0.f;
        #pragma unroll
        for (int l = 0; l < DIM; ++l) a = fmaf(As[t][l], center[m * DIM + l], a);
        Acs[t] = a;
        red[t] = a * center[m * DIM + t];
    }
    __syncthreads();

    const int mt = m >> 4, ml = m & 15;
    for (int idx = t; idx < NSTEP * 32; idx += 256) {
        const int s = idx >> 5, k = idx & 31;
        float c;
        if (s == 0)       c = As[k][k] - 1.0f;
        else if (s <= 15) c = 2.0f * As[k][(k + s) & 31];
        else if (s == 16) c = (k < 16) ? 2.0f * As[k][k + 16] : -2.0f * Acs[k - 16];
        else              c = (k < 16) ? -2.0f * Acs[k + 16] : 0.0f;
        G[s * 8192 + mt * 512 + (k >> 3) * 128 + ml * 8 + (k & 7)] = (short)f2bf(c);
    }

    if (t < 64) {
        // register GE, no pivot: lane j owns column j.
        float logdet = 0.f;
        if (t < DIM) {
            float col[DIM];
            #pragma unroll
            for (int r2 = 0; r2 < DIM; ++r2) col[r2] = Ls[r2][t];
            float prodabs = 1.0f;
            #pragma unroll
            for (int k = 0; k < DIM; ++k) {
                const float pv  = __shfl(col[k], k, 64);
                const float rpv = 1.0f / pv;
                const float cjk = col[k];
                #pragma unroll
                for (int t2 = k + 1; t2 < DIM; ++t2) {
                    const float f = __shfl(col[t2], k, 64) * rpv;
                    col[t2] = fmaf(-f, cjk, col[t2]);
                }
                prodabs *= fabsf(pv);
            }
            logdet = logf(prodabs);
        }

        float wsp = 0.f;
        for (int j = t; j < MCL; j += 64) wsp += fabsf(weight[j]);
        #pragma unroll
        for (int d2 = 1; d2 < 64; d2 <<= 1) wsp += __shfl_xor(wsp, d2, 64);

        if (t == 0) {
            float t3 = 0.f;
            #pragma unroll
            for (int j = 0; j < DIM; ++j) t3 += red[j];
            cst[m] = logf(fabsf(weight[m])) - logf(wsp) + logdet - 0.5f * t3;
        }
    }
}

// ---------------------------------------------------------------------------
// main kernel helpers: ALL element selection at compile time (R4 lesson).
// ---------------------------------------------------------------------------
template<int OFF2, int E>
__device__ __forceinline__ float welem(const f32x4 a0, const f32x4 a1, const f32x4 a2) {
    constexpr int idx = OFF2 + E;
    if constexpr (idx < 4)      return a0[idx & 3];
    else if constexpr (idx < 8) return a1[idx & 3];
    else                        return a2[idx & 3];
}

template<int S, int E>
__device__ __forceinline__ float xsel(const float (&xkr)[8], int kg) {
    if constexpr (S == 16)      return (kg < 2) ? xkr[E] : 1.0f;
    else if constexpr (S == 17) return (kg < 2) ? 1.0f : 0.0f;
    else                        return xkr[E];
}

template<int S, int Q, int OFF2>
__device__ __forceinline__ unsigned mkpair(const float (&xkr)[8], int kg,
                                           const f32x4 a0, const f32x4 a1, const f32x4 a2) {
    float w0, w1;
    if constexpr (S == 0) { w0 = xkr[2 * Q]; w1 = xkr[2 * Q + 1]; }
    else { w0 = welem<OFF2, 2 * Q>(a0, a1, a2); w1 = welem<OFF2, 2 * Q + 1>(a0, a1, a2); }
    const float p0 = xsel<S, 2 * Q>(xkr, kg)     * w0;
    const float p1 = xsel<S, 2 * Q + 1>(xkr, kg) * w1;
    __hip_bfloat162 h2 = __float22bfloat162_rn(make_float2(p0, p1));
    return *reinterpret_cast<unsigned*>(&h2);
}

// ---------------------------------------------------------------------------
// main: block = 128 pts x 256 cl, 4 waves, wave tile 64x128, K = 18*32 = 576.
// ZERO barriers in the K-loop: B fragments read DIRECTLY from global (G is
// 288 KB, L2-resident, coalesced 1KB/instr); A fragments generated in regs
// from f32 LDS window * resident x. Waves free-run; whole loop is one
// template-unrolled scheduling region -> compiler interleaves loads/VALU/MFMA.
// ---------------------------------------------------------------------------
template<int S>
__device__ __forceinline__ void k_step(
    const short* __restrict__ G,
    const float* __restrict__ Xs,
    const int (&rowh)[4],
    const float (&xk)[4][8],
    f32x4 (&acc)[4][8],
    int lane, int kg, int wc)
{
    // B fragments straight from global (L2-hot, same for every block)
    s8v bf[8];
    #pragma unroll
    for (int j = 0; j < 8; ++j)
        bf[j] = *(const s8v*)(G + (size_t)S * 8192 + (wc * 8 + j) * 512 + lane * 8);

    constexpr int shv  = (S == 17) ? 16 : S;
    constexpr int off2 = shv & 3;
    const int bq = ((kg * 8 + shv) & 31) & ~3;   // aligned 4-float base

    s8v af[4];
    #pragma unroll
    for (int i = 0; i < 4; ++i) {
        f32x4 a0 = {}, a1 = {}, a2 = {};
        if constexpr (S != 0) {
            const float* xr = Xs + rowh[i] + bq;
            a0 = *(const f32x4*)(xr);
            a1 = *(const f32x4*)(xr + 4);
            if constexpr (off2 != 0) a2 = *(const f32x4*)(xr + 8);
        }
        union { s8v v; unsigned u[4]; } U;
        U.u[0] = mkpair<S, 0, off2>(xk[i], kg, a0, a1, a2);
        U.u[1] = mkpair<S, 1, off2>(xk[i], kg, a0, a1, a2);
        U.u[2] = mkpair<S, 2, off2>(xk[i], kg, a0, a1, a2);
        U.u[3] = mkpair<S, 3, off2>(xk[i], kg, a0, a1, a2);
        af[i] = U.v;
    }

    #pragma unroll
    for (int i = 0; i < 4; ++i)
        #pragma unroll
        for (int j = 0; j < 8; ++j)
            acc[i][j] = __builtin_amdgcn_mfma_f32_16x16x32_bf16(
                af[i], bf[j], acc[i][j], 0, 0, 0);
}

template<int S>
__device__ __forceinline__ void k_loop(
    const short* __restrict__ G, const float* __restrict__ Xs,
    const int (&rowh)[4], const float (&xk)[4][8], f32x4 (&acc)[4][8],
    int lane, int kg, int wc)
{
    k_step<S>(G, Xs, rowh, xk, acc, lane, kg, wc);
    if constexpr (S + 1 < NSTEP)
        k_loop<S + 1>(G, Xs, rowh, xk, acc, lane, kg, wc);
}

__global__ __launch_bounds__(THREADS, 2) void gmm_mfma(
    const float* __restrict__ X,
    const short* __restrict__ G,
    const float* __restrict__ cstw,
    const float* __restrict__ thr,
    float* __restrict__ out)
{
    __shared__ __attribute__((aligned(16))) float Xs[BPTS * 44];  // 22.5 KB
    __shared__ float nrm_s[BPTS];
    __shared__ float cst_s[MCL];
    __shared__ float lse_m[BPTS];
    __shared__ float lse_d[BPTS];

    const int tid  = threadIdx.x;
    const int lane = tid & 63;
    const int w    = tid >> 6;     // wave 0..3
    const int wr   = w & 1;        // row group: 64 points
    const int wc   = w >> 1;       // col group: 128 clusters
    const int r    = lane & 15;
    const int kg   = lane >> 4;
    const int P0   = blockIdx.x * BPTS;

    // resident f32 x-slices from global
    int rowh[4];
    float xk[4][8];
    #pragma unroll
    for (int i = 0; i < 4; ++i) {
        const int row = wr * 64 + i * 16 + r;
        rowh[i] = row * 44;
        const float4* xg = reinterpret_cast<const float4*>(
            X + (size_t)(P0 + row) * DIM + kg * 8);
        const float4 a = xg[0], b = xg[1];
        xk[i][0] = a.x; xk[i][1] = a.y; xk[i][2] = a.z; xk[i][3] = a.w;
        xk[i][4] = b.x; xk[i][5] = b.y; xk[i][6] = b.z; xk[i][7] = b.w;
    }

    // stage Xs (f32, stride 44, first 8 duplicated at 32..39 for wrap) + norms
    const int p = tid >> 1, hf = tid & 1;
    {
        const float4* Xg = reinterpret_cast<const float4*>(
            X + (size_t)(P0 + p) * DIM + hf * 16);
        float part = 0.f;
        #pragma unroll
        for (int q = 0; q < 4; ++q) {
            const float4 v = Xg[q];
            const int kb = hf * 16 + 4 * q;
            Xs[p * 44 + kb + 0] = v.x;
            Xs[p * 44 + kb + 1] = v.y;
            Xs[p * 44 + kb + 2] = v.z;
            Xs[p * 44 + kb + 3] = v.w;
            if (!hf && q < 2) {
                Xs[p * 44 + 32 + kb + 0] = v.x;
                Xs[p * 44 + 32 + kb + 1] = v.y;
                Xs[p * 44 + 32 + kb + 2] = v.z;
                Xs[p * 44 + 32 + kb + 3] = v.w;
            }
            part = fmaf(v.x, v.x, part); part = fmaf(v.y, v.y, part);
            part = fmaf(v.z, v.z, part); part = fmaf(v.w, v.w, part);
        }
        part += __shfl_xor(part, 1, 64);
        if (!hf) nrm_s[p] = part;
        cst_s[tid] = cstw[tid];
    }
    __syncthreads();   // Xs ready; only barrier before epilogue

    f32x4 acc[4][8] = {};
    k_loop<0>(G, Xs, rowh, xk, acc, lane, kg, wc);

    // ---- epilogue: weighted LSE over this wave's 128 clusters
    float cstr[8];
    #pragma unroll
    for (int j = 0; j < 8; ++j)
        cstr[j] = cst_s[wc * 128 + j * 16 + r];

    float mx[16], sm[16];
    #pragma unroll
    for (int i = 0; i < 4; ++i)
        #pragma unroll
        for (int rg = 0; rg < 4; ++rg) {
            const int sl = i * 4 + rg;
            float m_ = -1e30f;
            #pragma unroll
            for (int j = 0; j < 8; ++j)
                m_ = fmaxf(m_, fmaf(acc[i][j][rg], -0.5f, cstr[j]));
            float s_ = 0.f;
            #pragma unroll
            for (int j = 0; j < 8; ++j)
                s_ += __expf(fmaf(acc[i][j][rg], -0.5f, cstr[j]) - m_);
            mx[sl] = m_; sm[sl] = s_;
        }

    #pragma unroll
    for (int d = 1; d < 16; d <<= 1) {
        #pragma unroll
        for (int sl = 0; sl < 16; ++sl) {
            const float pm = __shfl_xor(mx[sl], d, 64);
            const float ps = __shfl_xor(sm[sl], d, 64);
            const float nm = fmaxf(mx[sl], pm);
            sm[sl] = sm[sl] * __expf(mx[sl] - nm) + ps * __expf(pm - nm);
            mx[sl] = nm;
        }
    }

    if (wc == 0 && r == 0) {
        #pragma unroll
        for (int i = 0; i < 4; ++i)
            #pragma unroll
            for (int rg = 0; rg < 4; ++rg) {
                const int p2 = wr * 64 + i * 16 + kg * 4 + rg;
                lse_m[p2] = mx[i * 4 + rg];
                lse_d[p2] = sm[i * 4 + rg];
            }
    }
    __syncthreads();
    if (wc == 1 && r == 0) {
        const float thrv = thr[0];
        #pragma unroll
        for (int i = 0; i < 4; ++i)
            #pragma unroll
            for (int rg = 0; rg < 4; ++rg) {
                const int sl = i * 4 + rg;
                const int p2 = wr * 64 + i * 16 + kg * 4 + rg;
                const float om = lse_m[p2], os = lse_d[p2];
                const float nm = fmaxf(mx[sl], om);
                const float ss = sm[sl] * __expf(mx[sl] - nm) + os * __expf(om - nm);
                out[P0 + p2] = nm + __logf(ss) - 0.5f * nrm_s[p2] - thrv;
            }
    }
}

extern "C" void kernel_launch(void* const* d_in, const int* in_sizes, int n_in,
                              void* d_out, int out_size, void* d_ws, size_t ws_size,
                              hipStream_t stream)
{
    const float* X      = (const float*)d_in[0];
    const float* center = (const float*)d_in[1];
    const float* L      = (const float*)d_in[2];
    const float* weight = (const float*)d_in[3];
    const float* thr    = (const float*)d_in[4];
    float* out = (float*)d_out;

    // ws layout: cst [256] f32 | G [18*8192] bf16-as-short (~296 KB)
    float* cst = (float*)d_ws;
    short* G   = (short*)((char*)d_ws + 1024);

    gmm_prep<<<MCL, 256, 0, stream>>>(center, L, weight, G, cst);
    gmm_mfma<<<NPTS / BPTS, THREADS, 0, stream>>>(X, G, cst, thr, out);
}